// Round 5
// baseline (391.499 us; speedup 1.0000x reference)
//
#include <hip/hip_runtime.h>

// PeriodicDistance: fused gather + PBC-shift + norm + passthrough kernel.
//
// Inputs: pos[N,3] f32, box[1,3,3] f32, edge_index[2,E] i32,
//         shifts_idx[E,3] i32, batch_map[E] i32.
// Output (flat float32 — harness reads the WHOLE buffer as f32):
//   edge_index as float (2E) | edge_weight (E) | edge_vec (3E) |
//   shifts_idx as float (3E).
//
// R4 evidence: HBM traffic already minimal (FETCH 98.5MB, WRITE 229.8MB) but
// only 2.33 TB/s — L1 request-rate bound, 75% of line-touches from the 24
// scalar pos-gather loads per thread. R5 change: gather each atom position as
// ONE 12B dwordx3 load (struct f3) -> 8 gather requests/thread instead of 24.

struct f3 { float x, y, z; };   // 12 B, align 4 -> global_load_dwordx3

template <bool MULTI>
__global__ __launch_bounds__(256) void pd_kernel(
    const float* __restrict__ pos,
    const float* __restrict__ box,   // [n_struct,3,3] row-major
    const int*   __restrict__ ei,    // [2,E]
    const int*   __restrict__ sh,    // [E,3]
    const int*   __restrict__ bmap,  // [E]
    float* __restrict__ out,
    const long long E)
{
    const long long nG = E >> 2;                 // full groups of 4 edges
    float* out_ei = out;                 // 2E floats (converted ints)
    float* out_w  = out + 2 * E;         // E floats
    float* out_v  = out + 3 * E;         // 3E floats
    float* out_s  = out + 6 * E;         // 3E floats (converted ints)

    // Single-structure fast path: box in registers (uniform scalar loads).
    float b00, b01, b02, b10, b11, b12, b20, b21, b22;
    if (!MULTI) {
        b00 = box[0]; b01 = box[1]; b02 = box[2];
        b10 = box[3]; b11 = box[4]; b12 = box[5];
        b20 = box[6]; b21 = box[7]; b22 = box[8];
    }

    const long long stride = (long long)gridDim.x * blockDim.x;

    for (long long g = (long long)blockIdx.x * blockDim.x + threadIdx.x;
         g < nG; g += stride) {
        const long long e0 = g << 2;

        const int4 i4 = *reinterpret_cast<const int4*>(ei + e0);
        const int4 j4 = *reinterpret_cast<const int4*>(ei + E + e0);
        const int4 sA = *reinterpret_cast<const int4*>(sh + 3 * e0);
        const int4 sB = *reinterpret_cast<const int4*>(sh + 3 * e0 + 4);
        const int4 sC = *reinterpret_cast<const int4*>(sh + 3 * e0 + 8);

        // Pass-through outputs, CONVERTED to float (harness reads f32).
        *reinterpret_cast<float4*>(out_ei + e0) =
            make_float4((float)i4.x, (float)i4.y, (float)i4.z, (float)i4.w);
        *reinterpret_cast<float4*>(out_ei + E + e0) =
            make_float4((float)j4.x, (float)j4.y, (float)j4.z, (float)j4.w);
        *reinterpret_cast<float4*>(out_s + 3 * e0) =
            make_float4((float)sA.x, (float)sA.y, (float)sA.z, (float)sA.w);
        *reinterpret_cast<float4*>(out_s + 3 * e0 + 4) =
            make_float4((float)sB.x, (float)sB.y, (float)sB.z, (float)sB.w);
        *reinterpret_cast<float4*>(out_s + 3 * e0 + 8) =
            make_float4((float)sC.x, (float)sC.y, (float)sC.z, (float)sC.w);

        const int iv[4] = {i4.x, i4.y, i4.z, i4.w};
        const int jv[4] = {j4.x, j4.y, j4.z, j4.w};
        const int sv[12] = {sA.x, sA.y, sA.z, sA.w,
                            sB.x, sB.y, sB.z, sB.w,
                            sC.x, sC.y, sC.z, sC.w};
        int bv[4] = {0, 0, 0, 0};
        if (MULTI) {
            const int4 b4 = *reinterpret_cast<const int4*>(bmap + e0);
            bv[0] = b4.x; bv[1] = b4.y; bv[2] = b4.z; bv[3] = b4.w;
        }

        // Issue all 8 position gathers as 12B dwordx3 loads up front so they
        // overlap (independent vmem ops, compiler schedules together).
        f3 pjv[4], piv[4];
#pragma unroll
        for (int k = 0; k < 4; ++k) {
            piv[k] = *reinterpret_cast<const f3*>(pos + 3LL * iv[k]);
            pjv[k] = *reinterpret_cast<const f3*>(pos + 3LL * jv[k]);
        }

        float w[4], v[12];
#pragma unroll
        for (int k = 0; k < 4; ++k) {
            float B00, B01, B02, B10, B11, B12, B20, B21, B22;
            if (MULTI) {
                const float* bb = box + 9LL * bv[k];
                B00 = bb[0]; B01 = bb[1]; B02 = bb[2];
                B10 = bb[3]; B11 = bb[4]; B12 = bb[5];
                B20 = bb[6]; B21 = bb[7]; B22 = bb[8];
            } else {
                B00 = b00; B01 = b01; B02 = b02;
                B10 = b10; B11 = b11; B12 = b12;
                B20 = b20; B21 = b21; B22 = b22;
            }
            const float sx = (float)sv[3 * k + 0];
            const float sy = (float)sv[3 * k + 1];
            const float sz = (float)sv[3 * k + 2];
            // einsum 'en,enm->em': c[m] = sum_n s[n] * box[n][m]
            const float cx = sx * B00 + sy * B10 + sz * B20;
            const float cy = sx * B01 + sy * B11 + sz * B21;
            const float cz = sx * B02 + sy * B12 + sz * B22;

            const float dx = pjv[k].x - piv[k].x + cx;
            const float dy = pjv[k].y - piv[k].y + cy;
            const float dz = pjv[k].z - piv[k].z + cz;

            w[k] = sqrtf(dx * dx + dy * dy + dz * dz);
            v[3 * k + 0] = -dx;
            v[3 * k + 1] = -dy;
            v[3 * k + 2] = -dz;
        }

        *reinterpret_cast<float4*>(out_w + e0) =
            make_float4(w[0], w[1], w[2], w[3]);
        *reinterpret_cast<float4*>(out_v + 3 * e0) =
            make_float4(v[0], v[1], v[2], v[3]);
        *reinterpret_cast<float4*>(out_v + 3 * e0 + 4) =
            make_float4(v[4], v[5], v[6], v[7]);
        *reinterpret_cast<float4*>(out_v + 3 * e0 + 8) =
            make_float4(v[8], v[9], v[10], v[11]);
    }

    // Tail: E % 4 edges, scalar path (empty for E = 6.4M; kept for generality).
    const long long tail0 = nG << 2;
    for (long long e = tail0 + (long long)blockIdx.x * blockDim.x + threadIdx.x;
         e < E; e += stride) {
        const int i = ei[e];
        const int j = ei[E + e];
        const int s0 = sh[3 * e], s1 = sh[3 * e + 1], s2 = sh[3 * e + 2];
        out_ei[e]     = (float)i;
        out_ei[E + e] = (float)j;
        out_s[3 * e]     = (float)s0;
        out_s[3 * e + 1] = (float)s1;
        out_s[3 * e + 2] = (float)s2;

        float B00, B01, B02, B10, B11, B12, B20, B21, B22;
        if (MULTI) {
            const float* bb = box + 9LL * bmap[e];
            B00 = bb[0]; B01 = bb[1]; B02 = bb[2];
            B10 = bb[3]; B11 = bb[4]; B12 = bb[5];
            B20 = bb[6]; B21 = bb[7]; B22 = bb[8];
        } else {
            B00 = b00; B01 = b01; B02 = b02;
            B10 = b10; B11 = b11; B12 = b12;
            B20 = b20; B21 = b21; B22 = b22;
        }
        const float sx = (float)s0, sy = (float)s1, sz = (float)s2;
        const float cx = sx * B00 + sy * B10 + sz * B20;
        const float cy = sx * B01 + sy * B11 + sz * B21;
        const float cz = sx * B02 + sy * B12 + sz * B22;
        const float dx = pos[3LL * j + 0] - pos[3LL * i + 0] + cx;
        const float dy = pos[3LL * j + 1] - pos[3LL * i + 1] + cy;
        const float dz = pos[3LL * j + 2] - pos[3LL * i + 2] + cz;
        out_w[e] = sqrtf(dx * dx + dy * dy + dz * dz);
        out_v[3 * e + 0] = -dx;
        out_v[3 * e + 1] = -dy;
        out_v[3 * e + 2] = -dz;
    }
}

extern "C" void kernel_launch(void* const* d_in, const int* in_sizes, int n_in,
                              void* d_out, int out_size, void* d_ws, size_t ws_size,
                              hipStream_t stream) {
    const float* pos  = (const float*)d_in[0];
    const float* box  = (const float*)d_in[1];
    const int*   ei   = (const int*)d_in[2];
    const int*   sh   = (const int*)d_in[3];
    const int*   bmap = (const int*)d_in[4];
    float* out = (float*)d_out;

    const long long E = (long long)in_sizes[4];     // batch_map length
    const int n_struct = in_sizes[1] / 9;

    const int block = 256;
    long long nG = (E + 3) >> 2;
    long long blocks = (nG + block - 1) / block;
    if (blocks < 1) blocks = 1;
    if (blocks > 32768) blocks = 32768;

    if (n_struct == 1) {
        pd_kernel<false><<<(int)blocks, block, 0, stream>>>(
            pos, box, ei, sh, bmap, out, E);
    } else {
        pd_kernel<true><<<(int)blocks, block, 0, stream>>>(
            pos, box, ei, sh, bmap, out, E);
    }
}

// Round 8
// 371.129 us; speedup vs baseline: 1.0549x; 1.0549x over previous
//
#include <hip/hip_runtime.h>

// PeriodicDistance: fused gather + PBC-shift + norm + passthrough kernel.
//
// Inputs: pos[N,3] f32, box[1,3,3] f32, edge_index[2,E] i32,
//         shifts_idx[E,3] i32, batch_map[E] i32.
// Output (flat f32): edge_index (2E) | edge_weight (E) | edge_vec (3E) |
//   shifts_idx (3E)  — int outputs stored as converted floats.
//
// R4/R5 evidence: traffic ideal (FETCH 98.5MB / WRITE 229.8MB) but only
// 2.33 TB/s, VALUBusy 5.6%. Theory: streaming ~330MB/call through the 4MiB
// per-XCD L2s evicts the 2.4MB pos working set -> random gathers miss L2 and
// eat L3/HBM latency. R6 change: NONTEMPORAL hints on all streaming loads and
// stores (no-allocate) so L2 stays reserved for pos; gathers stay cacheable.

typedef int   vint4   __attribute__((ext_vector_type(4)));
typedef float vfloat4 __attribute__((ext_vector_type(4)));

struct f3 { float x, y, z; };   // 12 B gather (global_load_dwordx3)

template <bool MULTI>
__global__ __launch_bounds__(256) void pd_kernel(
    const float* __restrict__ pos,
    const float* __restrict__ box,   // [n_struct,3,3] row-major
    const int*   __restrict__ ei,    // [2,E]
    const int*   __restrict__ sh,    // [E,3]
    const int*   __restrict__ bmap,  // [E]
    float* __restrict__ out,
    const long long E)
{
    const long long nG = E >> 2;                 // full groups of 4 edges
    float* out_ei = out;                 // 2E floats (converted ints)
    float* out_w  = out + 2 * E;         // E floats
    float* out_v  = out + 3 * E;         // 3E floats
    float* out_s  = out + 6 * E;         // 3E floats (converted ints)

    // Single-structure fast path: box in registers (uniform scalar loads).
    float b00, b01, b02, b10, b11, b12, b20, b21, b22;
    if (!MULTI) {
        b00 = box[0]; b01 = box[1]; b02 = box[2];
        b10 = box[3]; b11 = box[4]; b12 = box[5];
        b20 = box[6]; b21 = box[7]; b22 = box[8];
    }

    const long long stride = (long long)gridDim.x * blockDim.x;

    for (long long g = (long long)blockIdx.x * blockDim.x + threadIdx.x;
         g < nG; g += stride) {
        const long long e0 = g << 2;

        // Streaming reads: nontemporal (read-once, don't pollute L1/L2).
        const vint4 i4 = __builtin_nontemporal_load(
            reinterpret_cast<const vint4*>(ei + e0));
        const vint4 j4 = __builtin_nontemporal_load(
            reinterpret_cast<const vint4*>(ei + E + e0));
        const vint4 sA = __builtin_nontemporal_load(
            reinterpret_cast<const vint4*>(sh + 3 * e0));
        const vint4 sB = __builtin_nontemporal_load(
            reinterpret_cast<const vint4*>(sh + 3 * e0 + 4));
        const vint4 sC = __builtin_nontemporal_load(
            reinterpret_cast<const vint4*>(sh + 3 * e0 + 8));

        // Pass-through outputs, converted to float, nontemporal stores.
        {
            vfloat4 t;
            t = (vfloat4){(float)i4.x, (float)i4.y, (float)i4.z, (float)i4.w};
            __builtin_nontemporal_store(t, reinterpret_cast<vfloat4*>(out_ei + e0));
            t = (vfloat4){(float)j4.x, (float)j4.y, (float)j4.z, (float)j4.w};
            __builtin_nontemporal_store(t, reinterpret_cast<vfloat4*>(out_ei + E + e0));
            t = (vfloat4){(float)sA.x, (float)sA.y, (float)sA.z, (float)sA.w};
            __builtin_nontemporal_store(t, reinterpret_cast<vfloat4*>(out_s + 3 * e0));
            t = (vfloat4){(float)sB.x, (float)sB.y, (float)sB.z, (float)sB.w};
            __builtin_nontemporal_store(t, reinterpret_cast<vfloat4*>(out_s + 3 * e0 + 4));
            t = (vfloat4){(float)sC.x, (float)sC.y, (float)sC.z, (float)sC.w};
            __builtin_nontemporal_store(t, reinterpret_cast<vfloat4*>(out_s + 3 * e0 + 8));
        }

        const int iv[4] = {i4.x, i4.y, i4.z, i4.w};
        const int jv[4] = {j4.x, j4.y, j4.z, j4.w};
        const int sv[12] = {sA.x, sA.y, sA.z, sA.w,
                            sB.x, sB.y, sB.z, sB.w,
                            sC.x, sC.y, sC.z, sC.w};
        int bv[4] = {0, 0, 0, 0};
        if (MULTI) {
            const vint4 b4 = __builtin_nontemporal_load(
                reinterpret_cast<const vint4*>(bmap + e0));
            bv[0] = b4.x; bv[1] = b4.y; bv[2] = b4.z; bv[3] = b4.w;
        }

        // Position gathers: REGULAR loads (want pos resident in L1/L2).
        f3 pjv[4], piv[4];
#pragma unroll
        for (int k = 0; k < 4; ++k) {
            piv[k] = *reinterpret_cast<const f3*>(pos + 3LL * iv[k]);
            pjv[k] = *reinterpret_cast<const f3*>(pos + 3LL * jv[k]);
        }

        float w[4], v[12];
#pragma unroll
        for (int k = 0; k < 4; ++k) {
            float B00, B01, B02, B10, B11, B12, B20, B21, B22;
            if (MULTI) {
                const float* bb = box + 9LL * bv[k];
                B00 = bb[0]; B01 = bb[1]; B02 = bb[2];
                B10 = bb[3]; B11 = bb[4]; B12 = bb[5];
                B20 = bb[6]; B21 = bb[7]; B22 = bb[8];
            } else {
                B00 = b00; B01 = b01; B02 = b02;
                B10 = b10; B11 = b11; B12 = b12;
                B20 = b20; B21 = b21; B22 = b22;
            }
            const float sx = (float)sv[3 * k + 0];
            const float sy = (float)sv[3 * k + 1];
            const float sz = (float)sv[3 * k + 2];
            // einsum 'en,enm->em': c[m] = sum_n s[n] * box[n][m]
            const float cx = sx * B00 + sy * B10 + sz * B20;
            const float cy = sx * B01 + sy * B11 + sz * B21;
            const float cz = sx * B02 + sy * B12 + sz * B22;

            const float dx = pjv[k].x - piv[k].x + cx;
            const float dy = pjv[k].y - piv[k].y + cy;
            const float dz = pjv[k].z - piv[k].z + cz;

            w[k] = sqrtf(dx * dx + dy * dy + dz * dz);
            v[3 * k + 0] = -dx;
            v[3 * k + 1] = -dy;
            v[3 * k + 2] = -dz;
        }

        __builtin_nontemporal_store(
            (vfloat4){w[0], w[1], w[2], w[3]},
            reinterpret_cast<vfloat4*>(out_w + e0));
        __builtin_nontemporal_store(
            (vfloat4){v[0], v[1], v[2], v[3]},
            reinterpret_cast<vfloat4*>(out_v + 3 * e0));
        __builtin_nontemporal_store(
            (vfloat4){v[4], v[5], v[6], v[7]},
            reinterpret_cast<vfloat4*>(out_v + 3 * e0 + 4));
        __builtin_nontemporal_store(
            (vfloat4){v[8], v[9], v[10], v[11]},
            reinterpret_cast<vfloat4*>(out_v + 3 * e0 + 8));
    }

    // Tail: E % 4 edges, scalar path (empty for E = 6.4M; kept for generality).
    const long long tail0 = nG << 2;
    for (long long e = tail0 + (long long)blockIdx.x * blockDim.x + threadIdx.x;
         e < E; e += stride) {
        const int i = ei[e];
        const int j = ei[E + e];
        const int s0 = sh[3 * e], s1 = sh[3 * e + 1], s2 = sh[3 * e + 2];
        out_ei[e]     = (float)i;
        out_ei[E + e] = (float)j;
        out_s[3 * e]     = (float)s0;
        out_s[3 * e + 1] = (float)s1;
        out_s[3 * e + 2] = (float)s2;

        float B00, B01, B02, B10, B11, B12, B20, B21, B22;
        if (MULTI) {
            const float* bb = box + 9LL * bmap[e];
            B00 = bb[0]; B01 = bb[1]; B02 = bb[2];
            B10 = bb[3]; B11 = bb[4]; B12 = bb[5];
            B20 = bb[6]; B21 = bb[7]; B22 = bb[8];
        } else {
            B00 = b00; B01 = b01; B02 = b02;
            B10 = b10; B11 = b11; B12 = b12;
            B20 = b20; B21 = b21; B22 = b22;
        }
        const float sx = (float)s0, sy = (float)s1, sz = (float)s2;
        const float cx = sx * B00 + sy * B10 + sz * B20;
        const float cy = sx * B01 + sy * B11 + sz * B21;
        const float cz = sx * B02 + sy * B12 + sz * B22;
        const float dx = pos[3LL * j + 0] - pos[3LL * i + 0] + cx;
        const float dy = pos[3LL * j + 1] - pos[3LL * i + 1] + cy;
        const float dz = pos[3LL * j + 2] - pos[3LL * i + 2] + cz;
        out_w[e] = sqrtf(dx * dx + dy * dy + dz * dz);
        out_v[3 * e + 0] = -dx;
        out_v[3 * e + 1] = -dy;
        out_v[3 * e + 2] = -dz;
    }
}

extern "C" void kernel_launch(void* const* d_in, const int* in_sizes, int n_in,
                              void* d_out, int out_size, void* d_ws, size_t ws_size,
                              hipStream_t stream) {
    const float* pos  = (const float*)d_in[0];
    const float* box  = (const float*)d_in[1];
    const int*   ei   = (const int*)d_in[2];
    const int*   sh   = (const int*)d_in[3];
    const int*   bmap = (const int*)d_in[4];
    float* out = (float*)d_out;

    const long long E = (long long)in_sizes[4];     // batch_map length
    const int n_struct = in_sizes[1] / 9;

    const int block = 256;
    long long nG = (E + 3) >> 2;
    long long blocks = (nG + block - 1) / block;
    if (blocks < 1) blocks = 1;
    if (blocks > 32768) blocks = 32768;

    if (n_struct == 1) {
        pd_kernel<false><<<(int)blocks, block, 0, stream>>>(
            pos, box, ei, sh, bmap, out, E);
    } else {
        pd_kernel<true><<<(int)blocks, block, 0, stream>>>(
            pos, box, ei, sh, bmap, out, E);
    }
}